// Round 20
// baseline (77.241 us; speedup 1.0000x reference)
//
#include <hip/hip_runtime.h>

#define N_USER   100000
#define N_ITEM   200000
#define N_NODES  300000
#define NNZ      4000000
#define EMB      64
#define N_LAYERS 3
#define BATCH    4096
#define NSLOT    (3*BATCH)   // 12288
#define MAXE     96          // bucket capacity; edges/node ~ Poisson(13.3)
#define BMWORDS  9376        // ceil(300000/32)

// ---------------- ws layout ----------------
// [0]         u16  table16[N_NODES]       600,000 B (pad 600,064)  -- NEVER cleared (bitmap-gated)
// [600064]    int  count[NSLOT]           49,152 B
// [649216]    int2 csr2[NSLOT*MAXE]       9,437,184 B  (col, val-bits)
// [10086400]  uint bitmap[BMWORDS]        37,504 B

__global__ void k_setup(const int* __restrict__ users,
                        const int* __restrict__ pos,
                        const int* __restrict__ neg,
                        unsigned short* __restrict__ table16,
                        unsigned int* __restrict__ bitmap,
                        int* __restrict__ count) {
    int i = blockIdx.x * blockDim.x + threadIdx.x;
    if (i >= NSLOT) return;
    count[i] = 0;
    int node;
    if (i < BATCH)            node = users[i];
    else if (i < 2 * BATCH)   node = N_USER + pos[i - BATCH];
    else                      node = N_USER + neg[i - 2 * BATCH];
    table16[node] = (unsigned short)i;        // benign race on duplicates (winner consistent)
    atomicOr(&bitmap[((unsigned)node) >> 5], 1u << (node & 31));
}

// direct build (R17 proven): stream row+col+vals coalesced (4 edges/thread);
// bitmap gate (L1-resident, ~4.3% pass) -> rare table16 gather + count atomic
// + int2 store.
__global__ void __launch_bounds__(256) k_build(
        const int* __restrict__ row,
        const int* __restrict__ col,
        const float* __restrict__ vals,
        const unsigned int* __restrict__ bitmap,
        const unsigned short* __restrict__ table16,
        int* __restrict__ count,
        int2* __restrict__ csr2) {
    int t = blockIdx.x * 256 + threadIdx.x;   // int4-tile index (4 edges)
    if (t >= NNZ / 4) return;
    int4   r = ((const int4*)row)[t];
    int4   c = ((const int4*)col)[t];
    float4 v = ((const float4*)vals)[t];
    bool h0 = (bitmap[((unsigned)r.x) >> 5] >> (r.x & 31)) & 1;
    bool h1 = (bitmap[((unsigned)r.y) >> 5] >> (r.y & 31)) & 1;
    bool h2 = (bitmap[((unsigned)r.z) >> 5] >> (r.z & 31)) & 1;
    bool h3 = (bitmap[((unsigned)r.w) >> 5] >> (r.w & 31)) & 1;
    int rr[4] = { r.x, r.y, r.z, r.w };
    int cc[4] = { c.x, c.y, c.z, c.w };
    float vv[4] = { v.x, v.y, v.z, v.w };
    bool hh[4] = { h0, h1, h2, h3 };
    #pragma unroll
    for (int i = 0; i < 4; ++i) {
        if (hh[i]) {
            int si = (int)table16[rr[i]];
            int p = atomicAdd(&count[si], 1);
            if (p < MAXE)
                csr2[(size_t)si * MAXE + p] = make_int2(cc[i], __float_as_int(vv[i]));
        }
    }
}

// fused gather + MLP. Gather: fixed fully-unrolled 4 rounds of 4-edge float4
// loads (all 16 loads/slot independent -> compiler software-pipelines).
// MLP: float2-interleaved weights in LDS (1 ds_read_b64/i) + packed float2
// accumulator (v_pk_fma candidate).
__global__ void __launch_bounds__(512) k_gmlp(
        const int* __restrict__ users,
        const int* __restrict__ pos,
        const int* __restrict__ neg,
        const float* __restrict__ user_emb,
        const float* __restrict__ item_emb,
        const float* __restrict__ W_gc,
        const float* __restrict__ b_gc,
        const float* __restrict__ W_bi,
        const float* __restrict__ b_bi,
        const unsigned short* __restrict__ table16,
        const int* __restrict__ count,
        const int2* __restrict__ csr2,
        float* __restrict__ out) {
    __shared__ float2 wgb[EMB * EMB];     // {wg, wb} interleaved
    int tid = threadIdx.x;
    int w = tid >> 6;
    int j = tid & 63;
    int g = j >> 4;                // group 0..3 (one edge per group per round)
    int L = j & 15;                // lane within group: dims 4L..4L+3
    int sbase = blockIdx.x * 16 + w * 2;

    // stage layer-0 weights (interleaved); sync comes after the gather
    {
        const float4* g4 = (const float4*)W_gc;
        const float4* b4 = (const float4*)W_bi;
        #pragma unroll
        for (int i2 = tid; i2 < EMB * EMB / 4; i2 += 512) {
            float4 a = g4[i2];
            float4 b = b4[i2];
            wgb[i2 * 4 + 0] = make_float2(a.x, b.x);
            wgb[i2 * 4 + 1] = make_float2(a.y, b.y);
            wgb[i2 * 4 + 2] = make_float2(a.z, b.z);
            wgb[i2 * 4 + 3] = make_float2(a.w, b.w);
        }
    }

    // ---- phase 1: metadata chains for both slots ----
    float e[2];
    int   n[2];
    const int2* base[2];
    int2  ev[2];
    #pragma unroll
    for (int s = 0; s < 2; ++s) {
        int slot = sbase + s;
        int node;
        if (slot < BATCH)          node = users[slot];
        else if (slot < 2 * BATCH) node = N_USER + pos[slot - BATCH];
        else                       node = N_USER + neg[slot - 2 * BATCH];
        const float* erow = (node < N_USER) ? (user_emb + (size_t)node * EMB)
                                            : (item_emb + (size_t)(node - N_USER) * EMB);
        e[s] = erow[j];
        out[(size_t)slot * 256 + j] = e[s];       // layer-0 columns: raw ego

        int wslot = (int)table16[node];
        wslot = __builtin_amdgcn_readfirstlane(wslot);
        int nn = count[wslot];
        nn = (nn < MAXE) ? nn : MAXE;
        n[s] = __builtin_amdgcn_readfirstlane(nn);
        base[s] = csr2 + (size_t)wslot * MAXE;
        ev[s] = make_int2(0, 0);
        if (j < n[s]) ev[s] = base[s][j];         // lane j holds edge j
    }

    // ---- phase 2: fully-unrolled 4-round, 4-edge-parallel float4 gather ----
    float sval[2];
    #pragma unroll
    for (int s = 0; s < 2; ++s) {
        float4 acc4 = make_float4(0.f, 0.f, 0.f, 0.f);
        int nn = n[s];
        #pragma unroll
        for (int tt = 0; tt < 64; tt += 16) {     // fixed 4 rounds, masked
            float4 gv[4]; float vb[4];
            #pragma unroll
            for (int q = 0; q < 4; ++q) {
                int t = tt + q * 4 + g;
                int   bc = __shfl(ev[s].x, t, 64);
                float bv = __uint_as_float((unsigned)__shfl(ev[s].y, t, 64));
                bool okk = t < nn;
                int ci = okk ? bc : 0;
                vb[q] = okk ? bv : 0.f;
                const float* sp = (ci < N_USER) ? (user_emb + (size_t)ci * EMB)
                                                : (item_emb + (size_t)(ci - N_USER) * EMB);
                gv[q] = ((const float4*)sp)[L];   // 16 lanes x 16 B = 256 B row
            }
            #pragma unroll
            for (int q = 0; q < 4; ++q) {
                acc4.x = fmaf(vb[q], gv[q].x, acc4.x);
                acc4.y = fmaf(vb[q], gv[q].y, acc4.y);
                acc4.z = fmaf(vb[q], gv[q].z, acc4.z);
                acc4.w = fmaf(vb[q], gv[q].w, acc4.w);
            }
        }
        for (int t = 64 + g; t < nn; t += 4) {    // tail: essentially never
            int2 ee = base[s][t];
            float bv = __uint_as_float((unsigned)ee.y);
            const float* sp = (ee.x < N_USER) ? (user_emb + (size_t)ee.x * EMB)
                                              : (item_emb + (size_t)(ee.x - N_USER) * EMB);
            float4 gq = ((const float4*)sp)[L];
            acc4.x = fmaf(bv, gq.x, acc4.x);
            acc4.y = fmaf(bv, gq.y, acc4.y);
            acc4.z = fmaf(bv, gq.z, acc4.z);
            acc4.w = fmaf(bv, gq.w, acc4.w);
        }
        // cross-group reduce
        #pragma unroll
        for (int o = 16; o <= 32; o <<= 1) {
            acc4.x += __shfl_xor(acc4.x, o, 64);
            acc4.y += __shfl_xor(acc4.y, o, 64);
            acc4.z += __shfl_xor(acc4.z, o, 64);
            acc4.w += __shfl_xor(acc4.w, o, 64);
        }
        // remap: lane j wants dim j = comp (j&3) of lane (j>>2)
        int src = j >> 2;
        float c0 = __shfl(acc4.x, src, 64);
        float c1 = __shfl(acc4.y, src, 64);
        float c2 = __shfl(acc4.z, src, 64);
        float c3 = __shfl(acc4.w, src, 64);
        int r = j & 3;
        sval[s] = (r == 0) ? c0 : (r == 1) ? c1 : (r == 2) ? c2 : c3;
    }

    // ---- phase 3: 3-layer MLP with packed float2 accumulator ----
    for (int k = 0; k < N_LAYERS; ++k) {
        if (k == 0) {
            __syncthreads();                      // layer-0 weights staged
        } else {
            __syncthreads();                      // prev-layer LDS reads done
            const float4* g4 = (const float4*)(W_gc + (size_t)k * EMB * EMB);
            const float4* b4 = (const float4*)(W_bi + (size_t)k * EMB * EMB);
            #pragma unroll
            for (int i2 = tid; i2 < EMB * EMB / 4; i2 += 512) {
                float4 a = g4[i2];
                float4 b = b4[i2];
                wgb[i2 * 4 + 0] = make_float2(a.x, b.x);
                wgb[i2 * 4 + 1] = make_float2(a.y, b.y);
                wgb[i2 * 4 + 2] = make_float2(a.z, b.z);
                wgb[i2 * 4 + 3] = make_float2(a.w, b.w);
            }
            __syncthreads();                      // weights ready
        }

        float2 acc[2];
        float pv[2];
        float b1 = b_gc[k * EMB + j];
        float b2 = b_bi[k * EMB + j];
        #pragma unroll
        for (int s = 0; s < 2; ++s) { acc[s] = make_float2(b1, b2); pv[s] = sval[s] * e[s]; }

        #pragma unroll 8
        for (int i = 0; i < EMB; ++i) {
            float2 wv = wgb[i * EMB + j];         // single ds_read_b64
            #pragma unroll
            for (int s = 0; s < 2; ++s) {
                float si = __uint_as_float(__builtin_amdgcn_readlane(__float_as_uint(sval[s]), i));
                float pi = __uint_as_float(__builtin_amdgcn_readlane(__float_as_uint(pv[s]),   i));
                acc[s].x = fmaf(si, wv.x, acc[s].x);   // packs to v_pk_fma_f32
                acc[s].y = fmaf(pi, wv.y, acc[s].y);
            }
        }

        #pragma unroll
        for (int s = 0; s < 2; ++s) {
            float x = acc[s].x + acc[s].y;
            x = (x >= 0.f) ? x : 0.2f * x;        // leaky_relu 0.2
            float sq = x * x;                     // wave-wide L2 norm
            #pragma unroll
            for (int o = 32; o; o >>= 1) sq += __shfl_xor(sq, o, 64);
            float nn2 = fmaxf(sqrtf(sq), 1e-12f);
            out[(size_t)(sbase + s) * 256 + (k + 1) * 64 + j] = x / nn2;
            e[s] = x;                             // next-layer ego = unnormalized output
        }
    }
}

extern "C" void kernel_launch(void* const* d_in, const int* in_sizes, int n_in,
                              void* d_out, int out_size, void* d_ws, size_t ws_size,
                              hipStream_t stream) {
    const int*   users    = (const int*)  d_in[0];
    const int*   pos      = (const int*)  d_in[1];
    const int*   neg      = (const int*)  d_in[2];
    const int*   row      = (const int*)  d_in[3];
    const int*   col      = (const int*)  d_in[4];
    const float* vals     = (const float*)d_in[5];
    const float* user_emb = (const float*)d_in[6];
    const float* item_emb = (const float*)d_in[7];
    const float* W_gc     = (const float*)d_in[8];
    const float* b_gc     = (const float*)d_in[9];
    const float* W_bi     = (const float*)d_in[10];
    const float* b_bi     = (const float*)d_in[11];
    float* out = (float*)d_out;

    char* ws = (char*)d_ws;
    unsigned short* table16 = (unsigned short*)ws;
    int*            count   = (int*)(ws + 600064);
    int2*           csr2    = (int2*)(ws + 649216);
    unsigned int*   bitmap  = (unsigned int*)(ws + 10086400);

    hipMemsetAsync(bitmap, 0, (size_t)BMWORDS * sizeof(unsigned int), stream);
    k_setup<<<(NSLOT + 255) / 256, 256, 0, stream>>>(users, pos, neg, table16,
                                                     bitmap, count);
    k_build<<<(NNZ / 4 + 255) / 256, 256, 0, stream>>>(row, col, vals, bitmap,
                                                       table16, count, csr2);
    k_gmlp<<<NSLOT / 16, 512, 0, stream>>>(users, pos, neg, user_emb, item_emb,
                                           W_gc, b_gc, W_bi, b_bi,
                                           table16, count, csr2, out);
}

// Round 21
// 73.822 us; speedup vs baseline: 1.0463x; 1.0463x over previous
//
#include <hip/hip_runtime.h>

#define N_USER   100000
#define N_ITEM   200000
#define N_NODES  300000
#define NNZ      4000000
#define EMB      64
#define N_LAYERS 3
#define BATCH    4096
#define NSLOT    (3*BATCH)   // 12288
#define MAXE     96          // bucket capacity; edges/node ~ Poisson(13.3)
#define BMWORDS  9376        // ceil(300000/32)

// ---------------- ws layout ----------------
// [0]         u16  table16[N_NODES]       600,000 B (pad 600,064)  -- NEVER cleared (bitmap-gated)
// [600064]    int  count[NSLOT]           49,152 B
// [649216]    int2 csr2[NSLOT*MAXE]       9,437,184 B  (col, val-bits)
// [10086400]  uint bitmap[BMWORDS]        37,504 B

__global__ void k_setup(const int* __restrict__ users,
                        const int* __restrict__ pos,
                        const int* __restrict__ neg,
                        unsigned short* __restrict__ table16,
                        unsigned int* __restrict__ bitmap,
                        int* __restrict__ count) {
    int i = blockIdx.x * blockDim.x + threadIdx.x;
    if (i >= NSLOT) return;
    count[i] = 0;
    int node;
    if (i < BATCH)            node = users[i];
    else if (i < 2 * BATCH)   node = N_USER + pos[i - BATCH];
    else                      node = N_USER + neg[i - 2 * BATCH];
    table16[node] = (unsigned short)i;        // benign race on duplicates (winner consistent)
    atomicOr(&bitmap[((unsigned)node) >> 5], 1u << (node & 31));
}

// direct build (R17 proven): stream row+col+vals coalesced (4 edges/thread);
// bitmap gate (L1-resident, ~4.3% pass) -> rare table16 gather + count atomic
// + int2 store.
__global__ void __launch_bounds__(256) k_build(
        const int* __restrict__ row,
        const int* __restrict__ col,
        const float* __restrict__ vals,
        const unsigned int* __restrict__ bitmap,
        const unsigned short* __restrict__ table16,
        int* __restrict__ count,
        int2* __restrict__ csr2) {
    int t = blockIdx.x * 256 + threadIdx.x;   // int4-tile index (4 edges)
    if (t >= NNZ / 4) return;
    int4   r = ((const int4*)row)[t];
    int4   c = ((const int4*)col)[t];
    float4 v = ((const float4*)vals)[t];
    bool h0 = (bitmap[((unsigned)r.x) >> 5] >> (r.x & 31)) & 1;
    bool h1 = (bitmap[((unsigned)r.y) >> 5] >> (r.y & 31)) & 1;
    bool h2 = (bitmap[((unsigned)r.z) >> 5] >> (r.z & 31)) & 1;
    bool h3 = (bitmap[((unsigned)r.w) >> 5] >> (r.w & 31)) & 1;
    int rr[4] = { r.x, r.y, r.z, r.w };
    int cc[4] = { c.x, c.y, c.z, c.w };
    float vv[4] = { v.x, v.y, v.z, v.w };
    bool hh[4] = { h0, h1, h2, h3 };
    #pragma unroll
    for (int i = 0; i < 4; ++i) {
        if (hh[i]) {
            int si = (int)table16[rr[i]];
            int p = atomicAdd(&count[si], 1);
            if (p < MAXE)
                csr2[(size_t)si * MAXE + p] = make_int2(cc[i], __float_as_int(vv[i]));
        }
    }
}

// fused gather + MLP (R17 gather, byte-identical). MLP is now LDS-free and
// BARRIER-free: W read direct from global (32 KB/layer = L1-resident per CU;
// all waves walk the same lines), so waves run fully independently and a slow
// gather straggler no longer stalls its block.
__global__ void __launch_bounds__(512) k_gmlp(
        const int* __restrict__ users,
        const int* __restrict__ pos,
        const int* __restrict__ neg,
        const float* __restrict__ user_emb,
        const float* __restrict__ item_emb,
        const float* __restrict__ W_gc,
        const float* __restrict__ b_gc,
        const float* __restrict__ W_bi,
        const float* __restrict__ b_bi,
        const unsigned short* __restrict__ table16,
        const int* __restrict__ count,
        const int2* __restrict__ csr2,
        float* __restrict__ out) {
    int tid = threadIdx.x;
    int w = tid >> 6;
    int j = tid & 63;
    int g = j >> 4;                // group 0..3 (one edge per group per round)
    int L = j & 15;                // lane within group: dims 4L..4L+3
    int sbase = blockIdx.x * 16 + w * 2;

    // ---- phase 1: metadata chains for both slots ----
    float e[2];
    int   n[2];
    const int2* base[2];
    int2  ev[2];
    #pragma unroll
    for (int s = 0; s < 2; ++s) {
        int slot = sbase + s;
        int node;
        if (slot < BATCH)          node = users[slot];
        else if (slot < 2 * BATCH) node = N_USER + pos[slot - BATCH];
        else                       node = N_USER + neg[slot - 2 * BATCH];
        const float* erow = (node < N_USER) ? (user_emb + (size_t)node * EMB)
                                            : (item_emb + (size_t)(node - N_USER) * EMB);
        e[s] = erow[j];
        out[(size_t)slot * 256 + j] = e[s];       // layer-0 columns: raw ego

        int wslot = (int)table16[node];
        wslot = __builtin_amdgcn_readfirstlane(wslot);
        int nn = count[wslot];
        nn = (nn < MAXE) ? nn : MAXE;
        n[s] = __builtin_amdgcn_readfirstlane(nn);
        base[s] = csr2 + (size_t)wslot * MAXE;
        ev[s] = make_int2(0, 0);
        if (j < n[s]) ev[s] = base[s][j];         // lane j holds edge j
    }

    // ---- phase 2: 4-edge-parallel float4 gather (R17, runtime-bounded) ----
    float sval[2];
    #pragma unroll
    for (int s = 0; s < 2; ++s) {
        float4 acc4 = make_float4(0.f, 0.f, 0.f, 0.f);
        int m = (n[s] < 64) ? n[s] : 64;
        for (int tt = 0; tt < m; tt += 16) {      // 16 edges per iter, 4 loads in flight
            float4 gv[4]; float vb[4];
            #pragma unroll
            for (int q = 0; q < 4; ++q) {
                int t = tt + q * 4 + g;           // my group's edge this sub-round
                int   bc = __shfl(ev[s].x, t, 64);
                float bv = __uint_as_float((unsigned)__shfl(ev[s].y, t, 64));
                bool okk = t < m;
                int ci = okk ? bc : 0;
                vb[q] = okk ? bv : 0.f;
                const float* sp = (ci < N_USER) ? (user_emb + (size_t)ci * EMB)
                                                : (item_emb + (size_t)(ci - N_USER) * EMB);
                gv[q] = ((const float4*)sp)[L];   // 16 lanes x 16 B = 256 B row
            }
            #pragma unroll
            for (int q = 0; q < 4; ++q) {
                acc4.x = fmaf(vb[q], gv[q].x, acc4.x);
                acc4.y = fmaf(vb[q], gv[q].y, acc4.y);
                acc4.z = fmaf(vb[q], gv[q].z, acc4.z);
                acc4.w = fmaf(vb[q], gv[q].w, acc4.w);
            }
        }
        for (int t = 64 + g; t < n[s]; t += 4) {  // tail: essentially never
            int2 ee = base[s][t];
            float bv = __uint_as_float((unsigned)ee.y);
            const float* sp = (ee.x < N_USER) ? (user_emb + (size_t)ee.x * EMB)
                                              : (item_emb + (size_t)(ee.x - N_USER) * EMB);
            float4 gq = ((const float4*)sp)[L];
            acc4.x = fmaf(bv, gq.x, acc4.x);
            acc4.y = fmaf(bv, gq.y, acc4.y);
            acc4.z = fmaf(bv, gq.z, acc4.z);
            acc4.w = fmaf(bv, gq.w, acc4.w);
        }
        // cross-group reduce (groups all hold same dim layout)
        #pragma unroll
        for (int o = 16; o <= 32; o <<= 1) {
            acc4.x += __shfl_xor(acc4.x, o, 64);
            acc4.y += __shfl_xor(acc4.y, o, 64);
            acc4.z += __shfl_xor(acc4.z, o, 64);
            acc4.w += __shfl_xor(acc4.w, o, 64);
        }
        // remap: lane j wants dim j = comp (j&3) of lane (j>>2)
        int src = j >> 2;
        float c0 = __shfl(acc4.x, src, 64);
        float c1 = __shfl(acc4.y, src, 64);
        float c2 = __shfl(acc4.z, src, 64);
        float c3 = __shfl(acc4.w, src, 64);
        int r = j & 3;
        sval[s] = (r == 0) ? c0 : (r == 1) ? c1 : (r == 2) ? c2 : c3;
    }

    // ---- phase 3: 3-layer MLP, barrier-free, W direct from global (L1-hot) ----
    for (int k = 0; k < N_LAYERS; ++k) {
        const float* wgp = W_gc + (size_t)k * EMB * EMB;
        const float* wbp = W_bi + (size_t)k * EMB * EMB;
        float b1 = b_gc[k * EMB + j];
        float b2 = b_bi[k * EMB + j];
        float sum1[2], sum2[2], pv[2];
        #pragma unroll
        for (int s = 0; s < 2; ++s) { sum1[s] = b1; sum2[s] = b2; pv[s] = sval[s] * e[s]; }

        #pragma unroll 8
        for (int i = 0; i < EMB; ++i) {
            float wgi = wgp[i * EMB + j];         // coalesced; L1-hit after first touch
            float wbi = wbp[i * EMB + j];
            #pragma unroll
            for (int s = 0; s < 2; ++s) {
                float si = __uint_as_float(__builtin_amdgcn_readlane(__float_as_uint(sval[s]), i));
                float pi = __uint_as_float(__builtin_amdgcn_readlane(__float_as_uint(pv[s]),   i));
                sum1[s] = fmaf(si, wgi, sum1[s]);
                sum2[s] = fmaf(pi, wbi, sum2[s]);
            }
        }

        #pragma unroll
        for (int s = 0; s < 2; ++s) {
            float x = sum1[s] + sum2[s];
            x = (x >= 0.f) ? x : 0.2f * x;        // leaky_relu 0.2
            float sq = x * x;                     // wave-wide L2 norm
            #pragma unroll
            for (int o = 32; o; o >>= 1) sq += __shfl_xor(sq, o, 64);
            float nn2 = fmaxf(sqrtf(sq), 1e-12f);
            out[(size_t)(sbase + s) * 256 + (k + 1) * 64 + j] = x / nn2;
            e[s] = x;                             // next-layer ego = unnormalized output
        }
    }
}

extern "C" void kernel_launch(void* const* d_in, const int* in_sizes, int n_in,
                              void* d_out, int out_size, void* d_ws, size_t ws_size,
                              hipStream_t stream) {
    const int*   users    = (const int*)  d_in[0];
    const int*   pos      = (const int*)  d_in[1];
    const int*   neg      = (const int*)  d_in[2];
    const int*   row      = (const int*)  d_in[3];
    const int*   col      = (const int*)  d_in[4];
    const float* vals     = (const float*)d_in[5];
    const float* user_emb = (const float*)d_in[6];
    const float* item_emb = (const float*)d_in[7];
    const float* W_gc     = (const float*)d_in[8];
    const float* b_gc     = (const float*)d_in[9];
    const float* W_bi     = (const float*)d_in[10];
    const float* b_bi     = (const float*)d_in[11];
    float* out = (float*)d_out;

    char* ws = (char*)d_ws;
    unsigned short* table16 = (unsigned short*)ws;
    int*            count   = (int*)(ws + 600064);
    int2*           csr2    = (int2*)(ws + 649216);
    unsigned int*   bitmap  = (unsigned int*)(ws + 10086400);

    hipMemsetAsync(bitmap, 0, (size_t)BMWORDS * sizeof(unsigned int), stream);
    k_setup<<<(NSLOT + 255) / 256, 256, 0, stream>>>(users, pos, neg, table16,
                                                     bitmap, count);
    k_build<<<(NNZ / 4 + 255) / 256, 256, 0, stream>>>(row, col, vals, bitmap,
                                                       table16, count, csr2);
    k_gmlp<<<NSLOT / 16, 512, 0, stream>>>(users, pos, neg, user_emb, item_emb,
                                           W_gc, b_gc, W_bi, b_bi,
                                           table16, count, csr2, out);
}